// Round 16
// baseline (237.328 us; speedup 1.0000x reference)
//
#include <hip/hip_runtime.h>
#include <hip/hip_fp16.h>
#include <type_traits>

#define NN2 25000
#define NN1 50000
#define NN0 100000
#define EE2 250000
#define EE1 500000
#define EE0 1000000
#define NTOTC 175000
#define ETOTC 1750000
#define NB 684            // ceil(175104/256) buckets of 256 nodes (vg>>8)
#define CHUNK 2048        // edges per count/place block
#define NBLK 855          // ceil(ETOTC/CHUNK)
#define BN_EPS 1e-5f

static inline int cdiv(long a, long b) { return (int)((a + b - 1) / b); }

typedef _Float16 half8 __attribute__((ext_vector_type(8)));
typedef float f32x4 __attribute__((ext_vector_type(4)));

// ------------- single MFMA GEMM: out = act(bn?(in) @ W + bias) --------------
template <int K, int M, bool RELU, bool BNIN, typename OT>
__global__ __launch_bounds__(256) void mfma_gemm_kernel(
    const __half* __restrict__ in, const float* __restrict__ W,
    const float* __restrict__ bias,
    const float* __restrict__ sums, const float* __restrict__ sumsq,
    const float* __restrict__ g, const float* __restrict__ bt,
    OT* __restrict__ out, int n)
{
    constexpr int BM = 64;
    constexpr int LDA = K + 8;
    constexpr int NC = M / 16;
    __shared__ __align__(16) _Float16 Ah[BM * LDA];
    __shared__ __align__(16) _Float16 Wt[M * LDA];
    const int tid = threadIdx.x;
    const int r0 = blockIdx.x * BM;

    for (int idx = tid; idx < K * M; idx += 256) {
        int k = idx / M, m = idx % M;
        Wt[m * LDA + k] = (_Float16)W[idx];
    }
    for (int idx = tid; idx < BM * K; idx += 256) {
        int r = idx / K, k = idx % K;
        int gr = r0 + r;
        float v = (gr < n) ? __half2float(in[(long)gr * K + k]) : 0.f;
        if (BNIN) {
            float mu = sums[k] * (1.f / NN2);
            float rs = rsqrtf(sumsq[k] * (1.f / NN2) - mu * mu + BN_EPS);
            v = g[k] * rs * (v - mu) + bt[k];
        }
        Ah[r * LDA + k] = (_Float16)v;
    }
    __syncthreads();

    const int wid = tid >> 6, lane = tid & 63;
    const int rw = wid * 16;
    const int arow = rw + (lane & 15);
    const int koff = (lane >> 4) * 8;

    f32x4 acc[NC];
    #pragma unroll
    for (int c = 0; c < NC; ++c) acc[c] = f32x4{0.f, 0.f, 0.f, 0.f};
    #pragma unroll
    for (int k0 = 0; k0 < K; k0 += 32) {
        half8 a = *(const half8*)&Ah[arow * LDA + k0 + koff];
        #pragma unroll
        for (int c = 0; c < NC; ++c) {
            half8 b = *(const half8*)&Wt[(c * 16 + (lane & 15)) * LDA + k0 + koff];
            acc[c] = __builtin_amdgcn_mfma_f32_16x16x32_f16(a, b, acc[c], 0, 0, 0);
        }
    }
    const int drow = r0 + rw + 4 * (lane >> 4);
    #pragma unroll
    for (int c = 0; c < NC; ++c) {
        int col = c * 16 + (lane & 15);
        float bv = (bias != nullptr) ? bias[col] : 0.f;
        #pragma unroll
        for (int j = 0; j < 4; ++j) {
            int r = drow + j;
            if (r < n) {
                float v = acc[c][j] + bv;
                if (RELU) v = fmaxf(v, 0.f);
                if constexpr (std::is_same<OT, __half>::value)
                    out[(long)r * M + col] = __float2half(v);
                else
                    out[(long)r * M + col] = v;
            }
        }
    }
}

// ------ FUSED GIN layer: gather (64ch, + opt BN-affine of input stats) ------
// then MLP relu(relu(A@W1+b1)@W2+b2), BN-output stats. One kernel per layer.
template <int M1, int M2, bool BN>
__global__ __launch_bounds__(256) void gin_mlp_kernel(
    const __half* __restrict__ x, const int2* __restrict__ rpre,
    const int2* __restrict__ csr,
    const float* __restrict__ sums, const float* __restrict__ sumsq,
    const float* __restrict__ g, const float* __restrict__ bt,
    const float* __restrict__ W1, const float* __restrict__ b1,
    const float* __restrict__ W2, const float* __restrict__ b2,
    float* __restrict__ osum, float* __restrict__ osq,
    __half* __restrict__ out, int n)
{
    constexpr int BM = 64, K = 64;
    constexpr int LDA = K + 8;              // 72
    constexpr int LDM = M1 + 8;
    constexpr int S_AH = BM * LDA * 2;      // bytes
    constexpr int S_W1 = M1 * LDA * 2;
    constexpr int S_W2 = M2 * LDM * 2;
    constexpr int S_MID = BM * LDM * 2;
    constexpr int TOTAL = S_AH + S_W1 + S_W2;
    static_assert(S_MID + 8 * M2 <= S_AH + S_W1, "mid+bs must fit under Ah+Wt1");
    __shared__ __align__(16) char smem[TOTAL];
    _Float16* Ah  = (_Float16*)smem;
    _Float16* Wt1 = (_Float16*)(smem + S_AH);
    _Float16* Wt2 = (_Float16*)(smem + S_AH + S_W1);
    _Float16* mid = (_Float16*)smem;        // overlays Ah+Wt1 after stage 1
    float*    bs  = (float*)(smem + S_MID); // 2*M2 floats after mid

    const int tid = threadIdx.x;
    const int r0 = blockIdx.x * BM;

    // stage weights (Wt2 region disjoint; Wt1 read only in stage 1)
    for (int idx = tid; idx < K * M1; idx += 256) {
        int k = idx / M1, m = idx % M1;
        Wt1[m * LDA + k] = (_Float16)W1[idx];
    }
    for (int idx = tid; idx < M1 * M2; idx += 256) {
        int k = idx / M2, m = idx % M2;
        Wt2[m * LDM + k] = (_Float16)W2[idx];
    }

    // gather phase: 8 groups of 32 lanes; group grp fills rows grp, grp+8, ...
    {
        const int grp = tid >> 5, lane = tid & 31;
        for (int rr = grp; rr < BM; rr += 8) {
            int v = r0 + rr;
            float accx = 0.f, accy = 0.f;
            if (v < n) {
                int2 pr = rpre[v];
                int p0 = pr.x, pe = pr.y;
                float2 sv = __half22float2(*(const __half2*)(x + (long)v * 64 + lane * 2));
                float ax[8], ay[8];
                #pragma unroll
                for (int u = 0; u < 8; ++u) { ax[u] = 0.f; ay[u] = 0.f; }
                ax[0] = sv.x; ay[0] = sv.y;
                for (int base = p0; base < pe; base += 32) {
                    int idx = base + lane;
                    int s_l = 0; float m_l = 0.f;
                    if (idx < pe) { s_l = csr[idx].x; m_l = 1.f; }
                    int cnt = min(32, pe - base);
                    for (int j = 0; j < cnt; j += 8) {
                        int ss[8]; float mm[8];
                        #pragma unroll
                        for (int u = 0; u < 8; ++u) {
                            ss[u] = __shfl(s_l, j + u, 32);
                            mm[u] = __shfl(m_l, j + u, 32);
                        }
                        float2 hh[8];
                        #pragma unroll
                        for (int u = 0; u < 8; ++u)
                            hh[u] = __half22float2(*(const __half2*)(x + (long)ss[u] * 64 + lane * 2));
                        #pragma unroll
                        for (int u = 0; u < 8; ++u) {
                            ax[u] = fmaf(mm[u], hh[u].x, ax[u]);
                            ay[u] = fmaf(mm[u], hh[u].y, ay[u]);
                        }
                    }
                }
                accx = ((ax[0] + ax[1]) + (ax[2] + ax[3])) + ((ax[4] + ax[5]) + (ax[6] + ax[7]));
                accy = ((ay[0] + ay[1]) + (ay[2] + ay[3])) + ((ay[4] + ay[5]) + (ay[6] + ay[7]));
                if (BN) {
                    int deg = pe - p0;
                    int c0 = lane * 2, c1 = lane * 2 + 1;
                    float mu0 = sums[c0] * (1.f / NN2), mu1 = sums[c1] * (1.f / NN2);
                    float rs0 = rsqrtf(sumsq[c0] * (1.f / NN2) - mu0 * mu0 + BN_EPS);
                    float rs1 = rsqrtf(sumsq[c1] * (1.f / NN2) - mu1 * mu1 + BN_EPS);
                    float a0 = g[c0] * rs0, a1 = g[c1] * rs1;
                    accx = a0 * accx + (float)(deg + 1) * (bt[c0] - a0 * mu0);
                    accy = a1 * accy + (float)(deg + 1) * (bt[c1] - a1 * mu1);
                }
            }
            Ah[rr * LDA + lane * 2]     = (_Float16)accx;
            Ah[rr * LDA + lane * 2 + 1] = (_Float16)accy;
        }
    }
    __syncthreads();

    const int wid = tid >> 6, lane64 = tid & 63;
    const int rw = wid * 16;
    const int arow = rw + (lane64 & 15);
    const int koff = (lane64 >> 4) * 8;
    constexpr int NC1 = M1 / 16, NC2 = M2 / 16;

    // ---- stage 1 ----
    f32x4 acc1[NC1];
    #pragma unroll
    for (int c = 0; c < NC1; ++c) acc1[c] = f32x4{0.f, 0.f, 0.f, 0.f};
    #pragma unroll
    for (int k0 = 0; k0 < K; k0 += 32) {
        half8 a = *(const half8*)&Ah[arow * LDA + k0 + koff];
        #pragma unroll
        for (int c = 0; c < NC1; ++c) {
            half8 b = *(const half8*)&Wt1[(c * 16 + (lane64 & 15)) * LDA + k0 + koff];
            acc1[c] = __builtin_amdgcn_mfma_f32_16x16x32_f16(a, b, acc1[c], 0, 0, 0);
        }
    }
    __syncthreads();   // all Ah/Wt1 reads done; mid may now overlay them

    {
        int rd0 = rw + 4 * (lane64 >> 4);
        #pragma unroll
        for (int c = 0; c < NC1; ++c) {
            int col = c * 16 + (lane64 & 15);
            float bv = b1[col];
            #pragma unroll
            for (int j = 0; j < 4; ++j)
                mid[(rd0 + j) * LDM + col] = (_Float16)fmaxf(acc1[c][j] + bv, 0.f);
        }
    }
    if (tid < 2 * M2) bs[tid] = 0.f;
    __syncthreads();

    // ---- stage 2 ----
    f32x4 acc2[NC2];
    #pragma unroll
    for (int c = 0; c < NC2; ++c) acc2[c] = f32x4{0.f, 0.f, 0.f, 0.f};
    #pragma unroll
    for (int k0 = 0; k0 < M1; k0 += 32) {
        half8 a = *(const half8*)&mid[arow * LDM + k0 + koff];
        #pragma unroll
        for (int c = 0; c < NC2; ++c) {
            half8 b = *(const half8*)&Wt2[(c * 16 + (lane64 & 15)) * LDM + k0 + koff];
            acc2[c] = __builtin_amdgcn_mfma_f32_16x16x32_f16(a, b, acc2[c], 0, 0, 0);
        }
    }
    const int drow = r0 + rw + 4 * (lane64 >> 4);
    #pragma unroll
    for (int c = 0; c < NC2; ++c) {
        int col = c * 16 + (lane64 & 15);
        float bv = b2[col];
        float sc = 0.f, qc = 0.f;
        #pragma unroll
        for (int j = 0; j < 4; ++j) {
            int r = drow + j;
            if (r < n) {
                float v = fmaxf(acc2[c][j] + bv, 0.f);
                out[(long)r * M2 + col] = __float2half(v);
                sc += v; qc += v * v;
            }
        }
        atomicAdd(&bs[col], sc);
        atomicAdd(&bs[M2 + col], qc);
    }
    __syncthreads();
    if (tid < M2) { atomicAdd(&osum[tid], bs[tid]); atomicAdd(&osq[tid], bs[M2 + tid]); }
}

// ------- inverse perms + zero bn stats + x->fp16 convert (fused) ------------
__global__ void inv_tohalf_kernel(const int* __restrict__ perm1, const int* __restrict__ perm0,
                                  int* __restrict__ inv1, int* __restrict__ inv0,
                                  float* __restrict__ bnz,
                                  const float* __restrict__ x, __half* __restrict__ xh)
{
    int i = blockIdx.x * blockDim.x + threadIdx.x;
    if (i < 384) bnz[i] = 0.f;
    if (i < NN2) inv1[perm1[i]] = i;
    else if (i < NN2 + NN1) inv0[perm0[i - NN2]] = i - NN2;
    if (i < NN2 * 16) {
        float4 v = ((const float4*)x)[i];
        __half2 a = __floats2half2_rn(v.x, v.y);
        __half2 b = __floats2half2_rn(v.z, v.w);
        ((uint2*)xh)[i] = make_uint2(*(unsigned*)&a, *(unsigned*)&b);
    }
}

// ------- fused count (LDS hist of dst buckets) + translate (inv lookup) -----
__global__ __launch_bounds__(256) void count_translate_kernel(
    const int* __restrict__ dst2,
    const int* __restrict__ src1, const int* __restrict__ dst1,
    const int* __restrict__ src0, const int* __restrict__ dst0,
    const int* __restrict__ inv1, const int* __restrict__ inv0,
    int* __restrict__ tcg, int* __restrict__ G)
{
    __shared__ int h[NB];
    int tid = threadIdx.x, blk = blockIdx.x;
    for (int i = tid; i < NB; i += 256) h[i] = 0;
    __syncthreads();
    int e0 = blk * CHUNK, e1 = min(e0 + CHUNK, ETOTC);
    for (int e = e0 + tid; e < e1; e += 256) {
        int vg;
        if (e < EE2) {
            vg = dst2[e];
        } else if (e < EE2 + EE1) {
            int i = e - EE2;
            vg = NN2 + dst1[i];
            tcg[i] = inv1[src1[i]];
        } else {
            int i = e - EE2 - EE1;
            vg = NN2 + NN1 + dst0[i];
            tcg[EE1 + i] = inv0[src0[i]];
        }
        atomicAdd(&h[vg >> 8], 1);
    }
    __syncthreads();
    for (int i = tid; i < NB; i += 256) G[i * NBLK + blk] = h[i];
}

// in-place exclusive scan, 1024 items / block of 256 threads
__global__ __launch_bounds__(256) void scan_block_kernel(int* data, int* bsum, int n)
{
    __shared__ int sh[256];
    int tid = threadIdx.x;
    int base = blockIdx.x * 1024 + tid * 4;
    int v[4];
    #pragma unroll
    for (int i = 0; i < 4; ++i) v[i] = (base + i < n) ? data[base + i] : 0;
    int tot = v[0] + v[1] + v[2] + v[3];
    sh[tid] = tot;
    __syncthreads();
    for (int d = 1; d < 256; d <<= 1) {
        int add = (tid >= d) ? sh[tid - d] : 0;
        __syncthreads();
        sh[tid] += add;
        __syncthreads();
    }
    int run = sh[tid] - tot;
    #pragma unroll
    for (int i = 0; i < 4; ++i) {
        if (base + i < n) data[base + i] = run;
        run += v[i];
    }
    if (tid == 255) bsum[blockIdx.x] = sh[255];
}

__global__ __launch_bounds__(1024) void scan_bsum_kernel(int* bsum, int nb)
{
    __shared__ int sh[1024];
    int tid = threadIdx.x;
    int v = (tid < nb) ? bsum[tid] : 0;
    sh[tid] = v;
    __syncthreads();
    for (int d = 1; d < 1024; d <<= 1) {
        int add = (tid >= d) ? sh[tid - d] : 0;
        __syncthreads();
        sh[tid] += add;
        __syncthreads();
    }
    if (tid < nb) bsum[tid] = sh[tid] - v;
}

// ------- place (streaming; bsum folded); bedges = ((local<<16)|(c+1), ew) ---
__global__ __launch_bounds__(256) void place_kernel(
    const int* __restrict__ src2, const int* __restrict__ dst2,
    const int* __restrict__ dst1, const float* __restrict__ ew1,
    const int* __restrict__ dst0, const float* __restrict__ ew0,
    const int* __restrict__ tcg,
    const int* __restrict__ G, const int* __restrict__ bsum,
    int2* __restrict__ bedges)
{
    __shared__ int cur[NB];
    int tid = threadIdx.x, blk = blockIdx.x;
    for (int i = tid; i < NB; i += 256) {
        int idx = i * NBLK + blk;
        cur[i] = G[idx] + bsum[idx >> 10];
    }
    __syncthreads();
    int e0 = blk * CHUNK, e1 = min(e0 + CHUNK, ETOTC);
    for (int e = e0 + tid; e < e1; e += 256) {
        int vg, c, ewb;
        if (e < EE2) {
            vg = dst2[e]; c = src2[e]; ewb = 0;
        } else if (e < EE2 + EE1) {
            int i = e - EE2;
            vg = NN2 + dst1[i]; c = tcg[i]; ewb = __float_as_int(ew1[i]);
        } else {
            int i = e - EE2 - EE1;
            vg = NN2 + NN1 + dst0[i]; c = tcg[EE1 + i]; ewb = __float_as_int(ew0[i]);
        }
        int b = vg >> 8, local = vg & 255;
        int pos = atomicAdd(&cur[b], 1);
        bedges[pos] = make_int2((local << 16) | (c + 1), ewb);
    }
}

// ------- per-bucket (256 nodes) live-only CSR + rpre + dis (bsum folded) ----
__global__ __launch_bounds__(256) void bucket_build_kernel(
    const int2* __restrict__ bedges, const int* __restrict__ G,
    const int* __restrict__ bsum,
    int2* __restrict__ rpre,
    int2* __restrict__ csr, float* __restrict__ dis)
{
    __shared__ int cnt[256];
    __shared__ float wdeg[256];
    __shared__ int excl[256];
    __shared__ int tsum[256];
    int b = blockIdx.x, tid = threadIdx.x;
    int i0 = b * NBLK;
    int s0 = G[i0] + bsum[i0 >> 10];
    int s1;
    if (b == NB - 1) s1 = ETOTC;
    else { int i1 = (b + 1) * NBLK; s1 = G[i1] + bsum[i1 >> 10]; }
    cnt[tid] = 0; wdeg[tid] = 0.f;
    __syncthreads();
    for (int i = s0 + tid; i < s1; i += 256) {
        int2 t = bedges[i];
        int local = t.x >> 16;
        atomicAdd(&wdeg[local], __int_as_float(t.y));
        if (t.x & 0xFFFF) atomicAdd(&cnt[local], 1);
    }
    __syncthreads();
    int cv = cnt[tid];
    tsum[tid] = cv;
    __syncthreads();
    for (int d = 1; d < 256; d <<= 1) {
        int add = (tid >= d) ? tsum[tid - d] : 0;
        __syncthreads();
        tsum[tid] += add;
        __syncthreads();
    }
    excl[tid] = tsum[tid] - cv;
    {
        int vg = (b << 8) + tid;
        if (vg < NTOTC) {
            int r0_ = s0 + excl[tid];
            rpre[vg] = make_int2(r0_, r0_ + cv);
            if (vg >= NN2) dis[vg - NN2] = rsqrtf(wdeg[tid] + 2.0f);
        }
    }
    cnt[tid] = 0;
    __syncthreads();
    for (int i = s0 + tid; i < s1; i += 256) {
        int2 t = bedges[i];
        int cx = t.x & 0xFFFF;
        if (cx) {
            int local = t.x >> 16;
            int pos = s0 + excl[local] + atomicAdd(&cnt[local], 1);
            csr[pos] = make_int2(cx - 1, t.y);
        }
    }
}

// ---------------- compact-indexed dis tables --------------------------------
__global__ void disc_kernel(const int* __restrict__ perm1, const int* __restrict__ perm0,
                            const float* __restrict__ dis,
                            float* __restrict__ disc1, float* __restrict__ disc0)
{
    int i = blockIdx.x * blockDim.x + threadIdx.x;
    if (i < NN2) disc1[i] = dis[perm1[i]];
    else if (i < NN2 + NN1) disc0[i - NN2] = dis[NN1 + perm0[i - NN2]];
}

// ------ GCN gather 128ch: 32-lane group per node, 8-deep ILP ----------------
template <bool RELU>
__global__ __launch_bounds__(256) void gcn_gather128_kernel(
    const __half* __restrict__ cmp, const int* __restrict__ inv,
    const int2* __restrict__ rpre,
    const int2* __restrict__ csr, const float* __restrict__ disc,
    const float* __restrict__ dis, const float* __restrict__ bias,
    __half* __restrict__ out, int n)
{
    int v = (blockIdx.x * 256 + threadIdx.x) >> 5;
    int lane = threadIdx.x & 31;
    if (v >= n) return;
    int2 pr = rpre[v];
    int p0 = pr.x, pe = pr.y;
    f32x4 acc[8];
    #pragma unroll
    for (int u = 0; u < 8; ++u) acc[u] = f32x4{0.f, 0.f, 0.f, 0.f};
    for (int base = p0; base < pe; base += 32) {
        int idx = base + lane;
        int cs_l = 0; float w_l = 0.f;
        if (idx < pe) {
            int2 sl = csr[idx];
            cs_l = sl.x;
            w_l = __int_as_float(sl.y) * disc[sl.x];
        }
        int cnt = min(32, pe - base);
        for (int j = 0; j < cnt; j += 8) {
            int cc[8]; float ww[8];
            #pragma unroll
            for (int u = 0; u < 8; ++u) {
                cc[u] = __shfl(cs_l, j + u, 32);
                ww[u] = __shfl(w_l, j + u, 32);
            }
            uint2 uu[8];
            #pragma unroll
            for (int u = 0; u < 8; ++u)
                uu[u] = *(const uint2*)(cmp + (long)cc[u] * 128 + lane * 4);
            #pragma unroll
            for (int u = 0; u < 8; ++u) {
                float2 pa = __half22float2(*(__half2*)&uu[u].x);
                float2 pb = __half22float2(*(__half2*)&uu[u].y);
                acc[u][0] = fmaf(ww[u], pa.x, acc[u][0]);
                acc[u][1] = fmaf(ww[u], pa.y, acc[u][1]);
                acc[u][2] = fmaf(ww[u], pb.x, acc[u][2]);
                acc[u][3] = fmaf(ww[u], pb.y, acc[u][3]);
            }
        }
    }
    f32x4 tot = ((acc[0] + acc[1]) + (acc[2] + acc[3])) + ((acc[4] + acc[5]) + (acc[6] + acc[7]));
    float dv = dis[v];
    int cv = inv[v];
    float sx0 = 0.f, sx1 = 0.f, sx2 = 0.f, sx3 = 0.f;
    if (cv >= 0) {
        uint2 u = *(const uint2*)(cmp + (long)cv * 128 + lane * 4);
        float2 pa = __half22float2(*(__half2*)&u.x), pb = __half22float2(*(__half2*)&u.y);
        sx0 = pa.x; sx1 = pa.y; sx2 = pb.x; sx3 = pb.y;
    }
    float s2 = 2.f * dv * dv;
    float o0 = fmaf(dv, tot[0], fmaf(s2, sx0, bias[lane * 4]));
    float o1 = fmaf(dv, tot[1], fmaf(s2, sx1, bias[lane * 4 + 1]));
    float o2 = fmaf(dv, tot[2], fmaf(s2, sx2, bias[lane * 4 + 2]));
    float o3 = fmaf(dv, tot[3], fmaf(s2, sx3, bias[lane * 4 + 3]));
    if (RELU) {
        o0 = fmaxf(o0, 0.f); o1 = fmaxf(o1, 0.f);
        o2 = fmaxf(o2, 0.f); o3 = fmaxf(o3, 0.f);
    }
    __half2 ha = __floats2half2_rn(o0, o1), hb = __floats2half2_rn(o2, o3);
    *(uint2*)(out + (long)v * 128 + lane * 4) = make_uint2(*(unsigned*)&ha, *(unsigned*)&hb);
}

// ------ GCN gather 64ch: 32-lane group per node, 8-deep ILP -----------------
template <bool RELU>
__global__ __launch_bounds__(256) void gcn_gather64_kernel(
    const __half* __restrict__ cmp, const int* __restrict__ inv,
    const int2* __restrict__ rpre,
    const int2* __restrict__ csr, const float* __restrict__ disc,
    const float* __restrict__ dis, const float* __restrict__ bias,
    float* __restrict__ out, int n)
{
    int v = (blockIdx.x * 256 + threadIdx.x) >> 5;
    int lane = threadIdx.x & 31;
    if (v >= n) return;
    int2 pr = rpre[v];
    int p0 = pr.x, pe = pr.y;
    float ax[8], ay[8];
    #pragma unroll
    for (int u = 0; u < 8; ++u) { ax[u] = 0.f; ay[u] = 0.f; }
    for (int base = p0; base < pe; base += 32) {
        int idx = base + lane;
        int cs_l = 0; float w_l = 0.f;
        if (idx < pe) {
            int2 sl = csr[idx];
            cs_l = sl.x;
            w_l = __int_as_float(sl.y) * disc[sl.x];
        }
        int cnt = min(32, pe - base);
        for (int j = 0; j < cnt; j += 8) {
            int cc[8]; float ww[8];
            #pragma unroll
            for (int u = 0; u < 8; ++u) {
                cc[u] = __shfl(cs_l, j + u, 32);
                ww[u] = __shfl(w_l, j + u, 32);
            }
            float2 hh[8];
            #pragma unroll
            for (int u = 0; u < 8; ++u)
                hh[u] = __half22float2(*(const __half2*)(cmp + (long)cc[u] * 64 + lane * 2));
            #pragma unroll
            for (int u = 0; u < 8; ++u) {
                ax[u] = fmaf(ww[u], hh[u].x, ax[u]);
                ay[u] = fmaf(ww[u], hh[u].y, ay[u]);
            }
        }
    }
    float axs = ((ax[0] + ax[1]) + (ax[2] + ax[3])) + ((ax[4] + ax[5]) + (ax[6] + ax[7]));
    float ays = ((ay[0] + ay[1]) + (ay[2] + ay[3])) + ((ay[4] + ay[5]) + (ay[6] + ay[7]));
    float dv = dis[v];
    int cv = inv[v];
    float sx = 0.f, sy = 0.f;
    if (cv >= 0) {
        float2 hv = __half22float2(*(const __half2*)(cmp + (long)cv * 64 + lane * 2));
        sx = hv.x; sy = hv.y;
    }
    float s2 = 2.f * dv * dv;
    float o0 = fmaf(dv, axs, fmaf(s2, sx, bias[lane * 2]));
    float o1 = fmaf(dv, ays, fmaf(s2, sy, bias[lane * 2 + 1]));
    if (RELU) { o0 = fmaxf(o0, 0.f); o1 = fmaxf(o1, 0.f); }
    *(float2*)(out + (long)v * 64 + lane * 2) = make_float2(o0, o1);
}

// ---------------- launch ----------------------------------------------------
extern "C" void kernel_launch(void* const* d_in, const int* in_sizes, int n_in,
                              void* d_out, int out_size, void* d_ws, size_t ws_size,
                              hipStream_t stream)
{
    const float* x    = (const float*)d_in[0];
    const int*   ei2  = (const int*)d_in[1];
    const int*   ei0  = (const int*)d_in[4];
    const int*   ei1  = (const int*)d_in[5];
    const float* ew0  = (const float*)d_in[6];
    const float* ew1  = (const float*)d_in[7];
    const int*   perm0= (const int*)d_in[8];
    const int*   perm1= (const int*)d_in[9];
    const float* W1a  = (const float*)d_in[10];
    const float* b1a  = (const float*)d_in[11];
    const float* W1b  = (const float*)d_in[12];
    const float* b1b  = (const float*)d_in[13];
    const float* g1   = (const float*)d_in[14];
    const float* bt1  = (const float*)d_in[15];
    const float* W2a  = (const float*)d_in[16];
    const float* b2a  = (const float*)d_in[17];
    const float* W2b  = (const float*)d_in[18];
    const float* b2b  = (const float*)d_in[19];
    const float* g2   = (const float*)d_in[20];
    const float* bt2  = (const float*)d_in[21];
    const float* Wg0  = (const float*)d_in[22];
    const float* bg0  = (const float*)d_in[23];
    const float* Wg1  = (const float*)d_in[24];
    const float* bg1  = (const float*)d_in[25];
    float* out = (float*)d_out;

    float* ws  = (float*)d_ws;
    int*   wsi = (int*)d_ws;

    // ---- layout (float-element offsets); ws = 256 MB, using ~84 MB ----
    int2*  rpre  = (int2*)wsi;              // 175104 int2 -> 352000
    float* dis   = ws  + 352000;            // -> 502000
    float* disc1 = ws  + 502000;            // -> 527000
    float* disc0 = ws  + 527000;            // -> 577000
    int*   inv1  = wsi + 577000;            // -> 627000
    int*   inv0  = wsi + 627000;            // -> 727000
    float* s1    = ws  + 727000;            // s1(64) q1(64) s2(128) q2(128)
    float* q1    = ws  + 727064;
    float* s2    = ws  + 727128;
    float* q2    = ws  + 727256;            // -> 727384
    int*   bsum  = wsi + 727500;            // 1024 -> 728600
    int*   G     = wsi + 729000;            // NB*NBLK = 584820 -> 1,315,000
    int2*  bedges= (int2*)(wsi + 1315000);  // 1.75M int2 -> 4,815,000
    int2*  csr   = (int2*)(wsi + 4815000);  // -> 8,315,000
    __half* t0h  = (__half*)(ws + 9115000); // N2*64 h -> 9,915,000
    __half* Bb   = (__half*)(ws + 10715000);// N2*128 h -> 12,315,000
    __half* cmp1 = (__half*)(ws + 12315000);// N2*128 h -> 13,915,000
    __half* out1 = (__half*)(ws + 13915000);// N1*128 h -> 17,115,000
    __half* cmp0 = (__half*)(ws + 17115000);// N1*64 h -> 18,715,000
    int*   tcg   = wsi + 18715000;          // 1.5M -> 20,215,000
    __half* xh   = (__half*)(ws + 20215000);// N2*64 h -> 21,015,000

    const int* src2 = ei2, *dst2 = ei2 + EE2;
    const int* src1 = ei1, *dst1 = ei1 + EE1;
    const int* src0 = ei0, *dst0 = ei0 + EE0;

    const int NG = NB * NBLK;  // 584820

    // ---- prep ----
    hipMemsetAsync(inv1, 0xFF, (NN1 + NN0) * 4, stream);
    inv_tohalf_kernel<<<cdiv(NN2 * 16, 256), 256, 0, stream>>>(
        perm1, perm0, inv1, inv0, s1, x, xh);
    count_translate_kernel<<<NBLK, 256, 0, stream>>>(
        dst2, src1, dst1, src0, dst0, inv1, inv0, tcg, G);
    scan_block_kernel<<<cdiv(NG, 1024), 256, 0, stream>>>(G, bsum, NG);
    scan_bsum_kernel<<<1, 1024, 0, stream>>>(bsum, cdiv(NG, 1024));
    place_kernel<<<NBLK, 256, 0, stream>>>(
        src2, dst2, dst1, ew1, dst0, ew0, tcg, G, bsum, bedges);
    bucket_build_kernel<<<NB, 256, 0, stream>>>(bedges, G, bsum, rpre, csr, dis);
    disc_kernel<<<cdiv(NN2 + NN1, 256), 256, 0, stream>>>(perm1, perm0, dis, disc1, disc0);

    // ---- GIN layer 1: fused gather + MLP(64->64->64) + BN1 stats -----------
    gin_mlp_kernel<64, 64, false><<<cdiv(NN2, 64), 256, 0, stream>>>(
        xh, rpre, csr, nullptr, nullptr, nullptr, nullptr,
        W1a, b1a, W1b, b1b, s1, q1, t0h, NN2);

    // ---- GIN layer 2: fused gather (BN1 folded) + MLP(64->128->128) --------
    gin_mlp_kernel<128, 128, true><<<cdiv(NN2, 64), 256, 0, stream>>>(
        t0h, rpre, csr, s1, q1, g1, bt1,
        W2a, b2a, W2b, b2b, s2, q2, Bb, NN2);

    // ---- GCN level 1: cmp1 = BN2(Bb) @ Wg0 (MFMA), gather -> out1 ----------
    mfma_gemm_kernel<128, 128, false, true, __half><<<cdiv(NN2, 64), 256, 0, stream>>>(
        Bb, Wg0, nullptr, s2, q2, g2, bt2, cmp1, NN2);
    gcn_gather128_kernel<true><<<cdiv((long)NN1 * 32, 256), 256, 0, stream>>>(
        cmp1, inv1, rpre + NN2, csr, disc1, dis, bg0, out1, NN1);

    // ---- GCN level 0: cmp0 = out1 @ Wg1 (MFMA), gather -> d_out ------------
    mfma_gemm_kernel<128, 64, false, false, __half><<<cdiv(NN1, 64), 256, 0, stream>>>(
        out1, Wg1, nullptr, nullptr, nullptr, nullptr, nullptr, cmp0, NN1);
    gcn_gather64_kernel<false><<<cdiv((long)NN0 * 32, 256), 256, 0, stream>>>(
        cmp0, inv0, rpre + NN2 + NN1, csr, disc0, dis + NN1, bg1, out, NN0);
}

// Round 17
// 233.377 us; speedup vs baseline: 1.0169x; 1.0169x over previous
//
#include <hip/hip_runtime.h>
#include <hip/hip_fp16.h>
#include <type_traits>

#define NN2 25000
#define NN1 50000
#define NN0 100000
#define EE2 250000
#define EE1 500000
#define EE0 1000000
#define NTOTC 175000
#define ETOTC 1750000
#define NB 684            // ceil(175104/256) buckets of 256 nodes (vg>>8)
#define CHUNK 2048        // edges per count/place block
#define NBLK 855          // ceil(ETOTC/CHUNK)
#define BN_EPS 1e-5f

static inline int cdiv(long a, long b) { return (int)((a + b - 1) / b); }

typedef _Float16 half8 __attribute__((ext_vector_type(8)));
typedef float f32x4 __attribute__((ext_vector_type(4)));

// ------------- single MFMA GEMM: out = act(bn?(in) @ W + bias) --------------
template <int K, int M, bool RELU, bool BNIN, typename OT>
__global__ __launch_bounds__(256) void mfma_gemm_kernel(
    const __half* __restrict__ in, const float* __restrict__ W,
    const float* __restrict__ bias,
    const float* __restrict__ sums, const float* __restrict__ sumsq,
    const float* __restrict__ g, const float* __restrict__ bt,
    OT* __restrict__ out, int n)
{
    constexpr int BM = 64;
    constexpr int LDA = K + 8;
    constexpr int NC = M / 16;
    __shared__ __align__(16) _Float16 Ah[BM * LDA];
    __shared__ __align__(16) _Float16 Wt[M * LDA];
    const int tid = threadIdx.x;
    const int r0 = blockIdx.x * BM;

    for (int idx = tid; idx < K * M; idx += 256) {
        int k = idx / M, m = idx % M;
        Wt[m * LDA + k] = (_Float16)W[idx];
    }
    for (int idx = tid; idx < BM * K; idx += 256) {
        int r = idx / K, k = idx % K;
        int gr = r0 + r;
        float v = (gr < n) ? __half2float(in[(long)gr * K + k]) : 0.f;
        if (BNIN) {
            float mu = sums[k] * (1.f / NN2);
            float rs = rsqrtf(sumsq[k] * (1.f / NN2) - mu * mu + BN_EPS);
            v = g[k] * rs * (v - mu) + bt[k];
        }
        Ah[r * LDA + k] = (_Float16)v;
    }
    __syncthreads();

    const int wid = tid >> 6, lane = tid & 63;
    const int rw = wid * 16;
    const int arow = rw + (lane & 15);
    const int koff = (lane >> 4) * 8;

    f32x4 acc[NC];
    #pragma unroll
    for (int c = 0; c < NC; ++c) acc[c] = f32x4{0.f, 0.f, 0.f, 0.f};
    #pragma unroll
    for (int k0 = 0; k0 < K; k0 += 32) {
        half8 a = *(const half8*)&Ah[arow * LDA + k0 + koff];
        #pragma unroll
        for (int c = 0; c < NC; ++c) {
            half8 b = *(const half8*)&Wt[(c * 16 + (lane & 15)) * LDA + k0 + koff];
            acc[c] = __builtin_amdgcn_mfma_f32_16x16x32_f16(a, b, acc[c], 0, 0, 0);
        }
    }
    const int drow = r0 + rw + 4 * (lane >> 4);
    #pragma unroll
    for (int c = 0; c < NC; ++c) {
        int col = c * 16 + (lane & 15);
        float bv = (bias != nullptr) ? bias[col] : 0.f;
        #pragma unroll
        for (int j = 0; j < 4; ++j) {
            int r = drow + j;
            if (r < n) {
                float v = acc[c][j] + bv;
                if (RELU) v = fmaxf(v, 0.f);
                if constexpr (std::is_same<OT, __half>::value)
                    out[(long)r * M + col] = __float2half(v);
                else
                    out[(long)r * M + col] = v;
            }
        }
    }
}

// ------------- fused MLP: out = relu(relu(in@W1+b1)@W2+b2), BN-out stats ----
template <int K, int M1, int M2, bool BNOUT>
__global__ __launch_bounds__(256) void mlp_gemm_kernel(
    const __half* __restrict__ in,
    const float* __restrict__ W1, const float* __restrict__ b1,
    const float* __restrict__ W2, const float* __restrict__ b2,
    float* __restrict__ osum, float* __restrict__ osq,
    __half* __restrict__ out, int n)
{
    constexpr int BM = 64;
    constexpr int LDA = K + 8;
    constexpr int LDM = M1 + 8;
    constexpr int NC1 = M1 / 16, NC2 = M2 / 16;
    __shared__ __align__(16) _Float16 Ah[BM * LDA];
    __shared__ __align__(16) _Float16 Wt1[M1 * LDA];
    __shared__ __align__(16) _Float16 Wt2[M2 * LDM];
    __shared__ __align__(16) _Float16 mid[BM * LDM];
    const int tid = threadIdx.x;
    const int r0 = blockIdx.x * BM;

    for (int idx = tid; idx < K * M1; idx += 256) {
        int k = idx / M1, m = idx % M1;
        Wt1[m * LDA + k] = (_Float16)W1[idx];
    }
    for (int idx = tid; idx < M1 * M2; idx += 256) {
        int k = idx / M2, m = idx % M2;
        Wt2[m * LDM + k] = (_Float16)W2[idx];
    }
    for (int idx = tid; idx < BM * K; idx += 256) {
        int r = idx / K, k = idx % K;
        int gr = r0 + r;
        Ah[r * LDA + k] = (gr < n) ? (_Float16)in[(long)gr * K + k] : (_Float16)0.f;
    }
    __syncthreads();

    const int wid = tid >> 6, lane = tid & 63;
    const int rw = wid * 16;
    const int arow = rw + (lane & 15);
    const int koff = (lane >> 4) * 8;

    f32x4 acc1[NC1];
    #pragma unroll
    for (int c = 0; c < NC1; ++c) acc1[c] = f32x4{0.f, 0.f, 0.f, 0.f};
    #pragma unroll
    for (int k0 = 0; k0 < K; k0 += 32) {
        half8 a = *(const half8*)&Ah[arow * LDA + k0 + koff];
        #pragma unroll
        for (int c = 0; c < NC1; ++c) {
            half8 b = *(const half8*)&Wt1[(c * 16 + (lane & 15)) * LDA + k0 + koff];
            acc1[c] = __builtin_amdgcn_mfma_f32_16x16x32_f16(a, b, acc1[c], 0, 0, 0);
        }
    }
    {
        int rd0 = rw + 4 * (lane >> 4);
        #pragma unroll
        for (int c = 0; c < NC1; ++c) {
            int col = c * 16 + (lane & 15);
            float bv = b1[col];
            #pragma unroll
            for (int j = 0; j < 4; ++j)
                mid[(rd0 + j) * LDM + col] = (_Float16)fmaxf(acc1[c][j] + bv, 0.f);
        }
    }
    float* bs = (float*)Ah;
    if (BNOUT) {
        if (tid < 2 * M2) bs[tid] = 0.f;
    }
    __syncthreads();

    f32x4 acc2[NC2];
    #pragma unroll
    for (int c = 0; c < NC2; ++c) acc2[c] = f32x4{0.f, 0.f, 0.f, 0.f};
    #pragma unroll
    for (int k0 = 0; k0 < M1; k0 += 32) {
        half8 a = *(const half8*)&mid[arow * LDM + k0 + koff];
        #pragma unroll
        for (int c = 0; c < NC2; ++c) {
            half8 b = *(const half8*)&Wt2[(c * 16 + (lane & 15)) * LDM + k0 + koff];
            acc2[c] = __builtin_amdgcn_mfma_f32_16x16x32_f16(a, b, acc2[c], 0, 0, 0);
        }
    }
    const int drow = r0 + rw + 4 * (lane >> 4);
    #pragma unroll
    for (int c = 0; c < NC2; ++c) {
        int col = c * 16 + (lane & 15);
        float bv = b2[col];
        float sc = 0.f, qc = 0.f;
        #pragma unroll
        for (int j = 0; j < 4; ++j) {
            int r = drow + j;
            if (r < n) {
                float v = fmaxf(acc2[c][j] + bv, 0.f);
                out[(long)r * M2 + col] = __float2half(v);
                if (BNOUT) { sc += v; qc += v * v; }
            }
        }
        if (BNOUT) { atomicAdd(&bs[col], sc); atomicAdd(&bs[M2 + col], qc); }
    }
    if (BNOUT) {
        __syncthreads();
        if (tid < M2) { atomicAdd(&osum[tid], bs[tid]); atomicAdd(&osq[tid], bs[M2 + tid]); }
    }
}

// ------- inverse perms + zero bn stats + x->fp16 convert (fused) ------------
__global__ void inv_tohalf_kernel(const int* __restrict__ perm1, const int* __restrict__ perm0,
                                  int* __restrict__ inv1, int* __restrict__ inv0,
                                  float* __restrict__ bnz,
                                  const float* __restrict__ x, __half* __restrict__ xh)
{
    int i = blockIdx.x * blockDim.x + threadIdx.x;
    if (i < 384) bnz[i] = 0.f;
    if (i < NN2) inv1[perm1[i]] = i;
    else if (i < NN2 + NN1) inv0[perm0[i - NN2]] = i - NN2;
    if (i < NN2 * 16) {
        float4 v = ((const float4*)x)[i];
        __half2 a = __floats2half2_rn(v.x, v.y);
        __half2 b = __floats2half2_rn(v.z, v.w);
        ((uint2*)xh)[i] = make_uint2(*(unsigned*)&a, *(unsigned*)&b);
    }
}

// ------- fused count (LDS hist of dst buckets) + translate (inv lookup) -----
__global__ __launch_bounds__(256) void count_translate_kernel(
    const int* __restrict__ dst2,
    const int* __restrict__ src1, const int* __restrict__ dst1,
    const int* __restrict__ src0, const int* __restrict__ dst0,
    const int* __restrict__ inv1, const int* __restrict__ inv0,
    int* __restrict__ tcg, int* __restrict__ G)
{
    __shared__ int h[NB];
    int tid = threadIdx.x, blk = blockIdx.x;
    for (int i = tid; i < NB; i += 256) h[i] = 0;
    __syncthreads();
    int e0 = blk * CHUNK, e1 = min(e0 + CHUNK, ETOTC);
    for (int e = e0 + tid; e < e1; e += 256) {
        int vg;
        if (e < EE2) {
            vg = dst2[e];
        } else if (e < EE2 + EE1) {
            int i = e - EE2;
            vg = NN2 + dst1[i];
            tcg[i] = inv1[src1[i]];
        } else {
            int i = e - EE2 - EE1;
            vg = NN2 + NN1 + dst0[i];
            tcg[EE1 + i] = inv0[src0[i]];
        }
        atomicAdd(&h[vg >> 8], 1);
    }
    __syncthreads();
    for (int i = tid; i < NB; i += 256) G[i * NBLK + blk] = h[i];
}

// in-place exclusive scan, 1024 items / block of 256 threads
__global__ __launch_bounds__(256) void scan_block_kernel(int* data, int* bsum, int n)
{
    __shared__ int sh[256];
    int tid = threadIdx.x;
    int base = blockIdx.x * 1024 + tid * 4;
    int v[4];
    #pragma unroll
    for (int i = 0; i < 4; ++i) v[i] = (base + i < n) ? data[base + i] : 0;
    int tot = v[0] + v[1] + v[2] + v[3];
    sh[tid] = tot;
    __syncthreads();
    for (int d = 1; d < 256; d <<= 1) {
        int add = (tid >= d) ? sh[tid - d] : 0;
        __syncthreads();
        sh[tid] += add;
        __syncthreads();
    }
    int run = sh[tid] - tot;
    #pragma unroll
    for (int i = 0; i < 4; ++i) {
        if (base + i < n) data[base + i] = run;
        run += v[i];
    }
    if (tid == 255) bsum[blockIdx.x] = sh[255];
}

__global__ __launch_bounds__(1024) void scan_bsum_kernel(int* bsum, int nb)
{
    __shared__ int sh[1024];
    int tid = threadIdx.x;
    int v = (tid < nb) ? bsum[tid] : 0;
    sh[tid] = v;
    __syncthreads();
    for (int d = 1; d < 1024; d <<= 1) {
        int add = (tid >= d) ? sh[tid - d] : 0;
        __syncthreads();
        sh[tid] += add;
        __syncthreads();
    }
    if (tid < nb) bsum[tid] = sh[tid] - v;
}

// ------- place (streaming; bsum folded); bedges = ((local<<16)|(c+1), ew) ---
__global__ __launch_bounds__(256) void place_kernel(
    const int* __restrict__ src2, const int* __restrict__ dst2,
    const int* __restrict__ dst1, const float* __restrict__ ew1,
    const int* __restrict__ dst0, const float* __restrict__ ew0,
    const int* __restrict__ tcg,
    const int* __restrict__ G, const int* __restrict__ bsum,
    int2* __restrict__ bedges)
{
    __shared__ int cur[NB];
    int tid = threadIdx.x, blk = blockIdx.x;
    for (int i = tid; i < NB; i += 256) {
        int idx = i * NBLK + blk;
        cur[i] = G[idx] + bsum[idx >> 10];
    }
    __syncthreads();
    int e0 = blk * CHUNK, e1 = min(e0 + CHUNK, ETOTC);
    for (int e = e0 + tid; e < e1; e += 256) {
        int vg, c, ewb;
        if (e < EE2) {
            vg = dst2[e]; c = src2[e]; ewb = 0;
        } else if (e < EE2 + EE1) {
            int i = e - EE2;
            vg = NN2 + dst1[i]; c = tcg[i]; ewb = __float_as_int(ew1[i]);
        } else {
            int i = e - EE2 - EE1;
            vg = NN2 + NN1 + dst0[i]; c = tcg[EE1 + i]; ewb = __float_as_int(ew0[i]);
        }
        int b = vg >> 8, local = vg & 255;
        int pos = atomicAdd(&cur[b], 1);
        bedges[pos] = make_int2((local << 16) | (c + 1), ewb);
    }
}

// ------- per-bucket (256 nodes) live-only CSR + rpre + dis (bsum folded) ----
__global__ __launch_bounds__(256) void bucket_build_kernel(
    const int2* __restrict__ bedges, const int* __restrict__ G,
    const int* __restrict__ bsum,
    int2* __restrict__ rpre,
    int2* __restrict__ csr, float* __restrict__ dis)
{
    __shared__ int cnt[256];
    __shared__ float wdeg[256];
    __shared__ int excl[256];
    __shared__ int tsum[256];
    int b = blockIdx.x, tid = threadIdx.x;
    int i0 = b * NBLK;
    int s0 = G[i0] + bsum[i0 >> 10];
    int s1;
    if (b == NB - 1) s1 = ETOTC;
    else { int i1 = (b + 1) * NBLK; s1 = G[i1] + bsum[i1 >> 10]; }
    cnt[tid] = 0; wdeg[tid] = 0.f;
    __syncthreads();
    for (int i = s0 + tid; i < s1; i += 256) {
        int2 t = bedges[i];
        int local = t.x >> 16;
        atomicAdd(&wdeg[local], __int_as_float(t.y));
        if (t.x & 0xFFFF) atomicAdd(&cnt[local], 1);
    }
    __syncthreads();
    int cv = cnt[tid];
    tsum[tid] = cv;
    __syncthreads();
    for (int d = 1; d < 256; d <<= 1) {
        int add = (tid >= d) ? tsum[tid - d] : 0;
        __syncthreads();
        tsum[tid] += add;
        __syncthreads();
    }
    excl[tid] = tsum[tid] - cv;
    {
        int vg = (b << 8) + tid;
        if (vg < NTOTC) {
            int r0_ = s0 + excl[tid];
            rpre[vg] = make_int2(r0_, r0_ + cv);
            if (vg >= NN2) dis[vg - NN2] = rsqrtf(wdeg[tid] + 2.0f);
        }
    }
    cnt[tid] = 0;
    __syncthreads();
    for (int i = s0 + tid; i < s1; i += 256) {
        int2 t = bedges[i];
        int cx = t.x & 0xFFFF;
        if (cx) {
            int local = t.x >> 16;
            int pos = s0 + excl[local] + atomicAdd(&cnt[local], 1);
            csr[pos] = make_int2(cx - 1, t.y);
        }
    }
}

// ---------------- compact-indexed dis tables --------------------------------
__global__ void disc_kernel(const int* __restrict__ perm1, const int* __restrict__ perm0,
                            const float* __restrict__ dis,
                            float* __restrict__ disc1, float* __restrict__ disc0)
{
    int i = blockIdx.x * blockDim.x + threadIdx.x;
    if (i < NN2) disc1[i] = dis[perm1[i]];
    else if (i < NN2 + NN1) disc0[i - NN2] = dis[NN1 + perm0[i - NN2]];
}

// --------- GIN gather: 32-lane group per node, 8-deep ILP, fp16 -------------
template <bool BN>
__global__ __launch_bounds__(256) void gin_gather_kernel(
    const __half* __restrict__ x, const int2* __restrict__ rpre,
    const int2* __restrict__ csr,
    const float* __restrict__ sums, const float* __restrict__ sumsq,
    const float* __restrict__ g, const float* __restrict__ bt,
    __half* __restrict__ out, int n)
{
    int v = (blockIdx.x * 256 + threadIdx.x) >> 5;
    int lane = threadIdx.x & 31;
    if (v >= n) return;
    int2 pr = rpre[v];
    int p0 = pr.x, pe = pr.y;
    float2 sv = __half22float2(*(const __half2*)(x + (long)v * 64 + lane * 2));
    float ax[8], ay[8];
    #pragma unroll
    for (int u = 0; u < 8; ++u) { ax[u] = 0.f; ay[u] = 0.f; }
    ax[0] = sv.x; ay[0] = sv.y;
    for (int base = p0; base < pe; base += 32) {
        int idx = base + lane;
        int s_l = 0; float m_l = 0.f;
        if (idx < pe) { s_l = csr[idx].x; m_l = 1.f; }
        int cnt = min(32, pe - base);
        for (int j = 0; j < cnt; j += 8) {
            int ss[8]; float mm[8];
            #pragma unroll
            for (int u = 0; u < 8; ++u) {
                ss[u] = __shfl(s_l, j + u, 32);
                mm[u] = __shfl(m_l, j + u, 32);
            }
            float2 hh[8];
            #pragma unroll
            for (int u = 0; u < 8; ++u)
                hh[u] = __half22float2(*(const __half2*)(x + (long)ss[u] * 64 + lane * 2));
            #pragma unroll
            for (int u = 0; u < 8; ++u) {
                ax[u] = fmaf(mm[u], hh[u].x, ax[u]);
                ay[u] = fmaf(mm[u], hh[u].y, ay[u]);
            }
        }
    }
    float accx = ((ax[0] + ax[1]) + (ax[2] + ax[3])) + ((ax[4] + ax[5]) + (ax[6] + ax[7]));
    float accy = ((ay[0] + ay[1]) + (ay[2] + ay[3])) + ((ay[4] + ay[5]) + (ay[6] + ay[7]));
    if (BN) {
        int deg = pe - p0;
        int c0 = lane * 2, c1 = lane * 2 + 1;
        float mu0 = sums[c0] * (1.f / NN2), mu1 = sums[c1] * (1.f / NN2);
        float rs0 = rsqrtf(sumsq[c0] * (1.f / NN2) - mu0 * mu0 + BN_EPS);
        float rs1 = rsqrtf(sumsq[c1] * (1.f / NN2) - mu1 * mu1 + BN_EPS);
        float a0 = g[c0] * rs0, a1 = g[c1] * rs1;
        accx = a0 * accx + (float)(deg + 1) * (bt[c0] - a0 * mu0);
        accy = a1 * accy + (float)(deg + 1) * (bt[c1] - a1 * mu1);
    }
    *(__half2*)(out + (long)v * 64 + lane * 2) = __floats2half2_rn(accx, accy);
}

// ------ GCN gather 128ch: 32-lane group per node, 8-deep ILP ----------------
template <bool RELU>
__global__ __launch_bounds__(256) void gcn_gather128_kernel(
    const __half* __restrict__ cmp, const int* __restrict__ inv,
    const int2* __restrict__ rpre,
    const int2* __restrict__ csr, const float* __restrict__ disc,
    const float* __restrict__ dis, const float* __restrict__ bias,
    __half* __restrict__ out, int n)
{
    int v = (blockIdx.x * 256 + threadIdx.x) >> 5;
    int lane = threadIdx.x & 31;
    if (v >= n) return;
    int2 pr = rpre[v];
    int p0 = pr.x, pe = pr.y;
    f32x4 acc[8];
    #pragma unroll
    for (int u = 0; u < 8; ++u) acc[u] = f32x4{0.f, 0.f, 0.f, 0.f};
    for (int base = p0; base < pe; base += 32) {
        int idx = base + lane;
        int cs_l = 0; float w_l = 0.f;
        if (idx < pe) {
            int2 sl = csr[idx];
            cs_l = sl.x;
            w_l = __int_as_float(sl.y) * disc[sl.x];
        }
        int cnt = min(32, pe - base);
        for (int j = 0; j < cnt; j += 8) {
            int cc[8]; float ww[8];
            #pragma unroll
            for (int u = 0; u < 8; ++u) {
                cc[u] = __shfl(cs_l, j + u, 32);
                ww[u] = __shfl(w_l, j + u, 32);
            }
            uint2 uu[8];
            #pragma unroll
            for (int u = 0; u < 8; ++u)
                uu[u] = *(const uint2*)(cmp + (long)cc[u] * 128 + lane * 4);
            #pragma unroll
            for (int u = 0; u < 8; ++u) {
                float2 pa = __half22float2(*(__half2*)&uu[u].x);
                float2 pb = __half22float2(*(__half2*)&uu[u].y);
                acc[u][0] = fmaf(ww[u], pa.x, acc[u][0]);
                acc[u][1] = fmaf(ww[u], pa.y, acc[u][1]);
                acc[u][2] = fmaf(ww[u], pb.x, acc[u][2]);
                acc[u][3] = fmaf(ww[u], pb.y, acc[u][3]);
            }
        }
    }
    f32x4 tot = ((acc[0] + acc[1]) + (acc[2] + acc[3])) + ((acc[4] + acc[5]) + (acc[6] + acc[7]));
    float dv = dis[v];
    int cv = inv[v];
    float sx0 = 0.f, sx1 = 0.f, sx2 = 0.f, sx3 = 0.f;
    if (cv >= 0) {
        uint2 u = *(const uint2*)(cmp + (long)cv * 128 + lane * 4);
        float2 pa = __half22float2(*(__half2*)&u.x), pb = __half22float2(*(__half2*)&u.y);
        sx0 = pa.x; sx1 = pa.y; sx2 = pb.x; sx3 = pb.y;
    }
    float s2 = 2.f * dv * dv;
    float o0 = fmaf(dv, tot[0], fmaf(s2, sx0, bias[lane * 4]));
    float o1 = fmaf(dv, tot[1], fmaf(s2, sx1, bias[lane * 4 + 1]));
    float o2 = fmaf(dv, tot[2], fmaf(s2, sx2, bias[lane * 4 + 2]));
    float o3 = fmaf(dv, tot[3], fmaf(s2, sx3, bias[lane * 4 + 3]));
    if (RELU) {
        o0 = fmaxf(o0, 0.f); o1 = fmaxf(o1, 0.f);
        o2 = fmaxf(o2, 0.f); o3 = fmaxf(o3, 0.f);
    }
    __half2 ha = __floats2half2_rn(o0, o1), hb = __floats2half2_rn(o2, o3);
    *(uint2*)(out + (long)v * 128 + lane * 4) = make_uint2(*(unsigned*)&ha, *(unsigned*)&hb);
}

// ------ GCN gather 64ch: 16-lane group per node (4 nodes/wave), 8-deep ------
template <bool RELU>
__global__ __launch_bounds__(256) void gcn_gather64_kernel(
    const __half* __restrict__ cmp, const int* __restrict__ inv,
    const int2* __restrict__ rpre,
    const int2* __restrict__ csr, const float* __restrict__ disc,
    const float* __restrict__ dis, const float* __restrict__ bias,
    float* __restrict__ out, int n)
{
    int v = (blockIdx.x * 256 + threadIdx.x) >> 4;
    int lane = threadIdx.x & 15;
    if (v >= n) return;
    int2 pr = rpre[v];
    int p0 = pr.x, pe = pr.y;
    f32x4 acc[8];
    #pragma unroll
    for (int u = 0; u < 8; ++u) acc[u] = f32x4{0.f, 0.f, 0.f, 0.f};
    for (int base = p0; base < pe; base += 16) {
        int idx = base + lane;
        int cs_l = 0; float w_l = 0.f;
        if (idx < pe) {
            int2 sl = csr[idx];
            cs_l = sl.x;
            w_l = __int_as_float(sl.y) * disc[sl.x];
        }
        int cnt = min(16, pe - base);
        for (int j = 0; j < cnt; j += 8) {
            int cc[8]; float ww[8];
            #pragma unroll
            for (int u = 0; u < 8; ++u) {
                cc[u] = __shfl(cs_l, j + u, 16);
                ww[u] = __shfl(w_l, j + u, 16);
            }
            uint2 uu[8];
            #pragma unroll
            for (int u = 0; u < 8; ++u)
                uu[u] = *(const uint2*)(cmp + (long)cc[u] * 64 + lane * 4);
            #pragma unroll
            for (int u = 0; u < 8; ++u) {
                float2 pa = __half22float2(*(__half2*)&uu[u].x);
                float2 pb = __half22float2(*(__half2*)&uu[u].y);
                acc[u][0] = fmaf(ww[u], pa.x, acc[u][0]);
                acc[u][1] = fmaf(ww[u], pa.y, acc[u][1]);
                acc[u][2] = fmaf(ww[u], pb.x, acc[u][2]);
                acc[u][3] = fmaf(ww[u], pb.y, acc[u][3]);
            }
        }
    }
    f32x4 tot = ((acc[0] + acc[1]) + (acc[2] + acc[3])) + ((acc[4] + acc[5]) + (acc[6] + acc[7]));
    float dv = dis[v];
    int cv = inv[v];
    float sx0 = 0.f, sx1 = 0.f, sx2 = 0.f, sx3 = 0.f;
    if (cv >= 0) {
        uint2 u = *(const uint2*)(cmp + (long)cv * 64 + lane * 4);
        float2 pa = __half22float2(*(__half2*)&u.x), pb = __half22float2(*(__half2*)&u.y);
        sx0 = pa.x; sx1 = pa.y; sx2 = pb.x; sx3 = pb.y;
    }
    float s2 = 2.f * dv * dv;
    float o0 = fmaf(dv, tot[0], fmaf(s2, sx0, bias[lane * 4]));
    float o1 = fmaf(dv, tot[1], fmaf(s2, sx1, bias[lane * 4 + 1]));
    float o2 = fmaf(dv, tot[2], fmaf(s2, sx2, bias[lane * 4 + 2]));
    float o3 = fmaf(dv, tot[3], fmaf(s2, sx3, bias[lane * 4 + 3]));
    if (RELU) {
        o0 = fmaxf(o0, 0.f); o1 = fmaxf(o1, 0.f);
        o2 = fmaxf(o2, 0.f); o3 = fmaxf(o3, 0.f);
    }
    *(float4*)(out + (long)v * 64 + lane * 4) = make_float4(o0, o1, o2, o3);
}

// ---------------- launch ----------------------------------------------------
extern "C" void kernel_launch(void* const* d_in, const int* in_sizes, int n_in,
                              void* d_out, int out_size, void* d_ws, size_t ws_size,
                              hipStream_t stream)
{
    const float* x    = (const float*)d_in[0];
    const int*   ei2  = (const int*)d_in[1];
    const int*   ei0  = (const int*)d_in[4];
    const int*   ei1  = (const int*)d_in[5];
    const float* ew0  = (const float*)d_in[6];
    const float* ew1  = (const float*)d_in[7];
    const int*   perm0= (const int*)d_in[8];
    const int*   perm1= (const int*)d_in[9];
    const float* W1a  = (const float*)d_in[10];
    const float* b1a  = (const float*)d_in[11];
    const float* W1b  = (const float*)d_in[12];
    const float* b1b  = (const float*)d_in[13];
    const float* g1   = (const float*)d_in[14];
    const float* bt1  = (const float*)d_in[15];
    const float* W2a  = (const float*)d_in[16];
    const float* b2a  = (const float*)d_in[17];
    const float* W2b  = (const float*)d_in[18];
    const float* b2b  = (const float*)d_in[19];
    const float* g2   = (const float*)d_in[20];
    const float* bt2  = (const float*)d_in[21];
    const float* Wg0  = (const float*)d_in[22];
    const float* bg0  = (const float*)d_in[23];
    const float* Wg1  = (const float*)d_in[24];
    const float* bg1  = (const float*)d_in[25];
    float* out = (float*)d_out;

    float* ws  = (float*)d_ws;
    int*   wsi = (int*)d_ws;

    // ---- layout (float-element offsets); ws = 256 MB, using ~84 MB ----
    int2*  rpre  = (int2*)wsi;              // 175104 int2 -> 352000
    float* dis   = ws  + 352000;            // -> 502000
    float* disc1 = ws  + 502000;            // -> 527000
    float* disc0 = ws  + 527000;            // -> 577000
    int*   inv1  = wsi + 577000;            // -> 627000
    int*   inv0  = wsi + 627000;            // -> 727000
    float* s1    = ws  + 727000;            // s1(64) q1(64) s2(128) q2(128)
    float* q1    = ws  + 727064;
    float* s2    = ws  + 727128;
    float* q2    = ws  + 727256;            // -> 727384
    int*   bsum  = wsi + 727500;            // 1024 -> 728600
    int*   G     = wsi + 729000;            // NB*NBLK = 584820 -> 1,315,000
    int2*  bedges= (int2*)(wsi + 1315000);  // 1.75M int2 -> 4,815,000
    int2*  csr   = (int2*)(wsi + 4815000);  // -> 8,315,000
    __half* t0f  = (__half*)(ws + 8315000); // N2*64 h -> 9,115,000
    __half* t0h  = (__half*)(ws + 9115000); // N2*64 h -> 9,915,000
    __half* t1   = (__half*)(ws + 9915000); // N2*64 h -> 10,715,000
    __half* Bb   = (__half*)(ws + 10715000);// N2*128 h -> 12,315,000
    __half* cmp1 = (__half*)(ws + 12315000);// N2*128 h -> 13,915,000
    __half* out1 = (__half*)(ws + 13915000);// N1*128 h -> 17,115,000
    __half* cmp0 = (__half*)(ws + 17115000);// N1*64 h -> 18,715,000
    int*   tcg   = wsi + 18715000;          // 1.5M -> 20,215,000
    __half* xh   = (__half*)(ws + 20215000);// N2*64 h -> 21,015,000

    const int* src2 = ei2, *dst2 = ei2 + EE2;
    const int* src1 = ei1, *dst1 = ei1 + EE1;
    const int* src0 = ei0, *dst0 = ei0 + EE0;

    const int NG = NB * NBLK;  // 584820

    // ---- prep ----
    hipMemsetAsync(inv1, 0xFF, (NN1 + NN0) * 4, stream);
    inv_tohalf_kernel<<<cdiv(NN2 * 16, 256), 256, 0, stream>>>(
        perm1, perm0, inv1, inv0, s1, x, xh);
    count_translate_kernel<<<NBLK, 256, 0, stream>>>(
        dst2, src1, dst1, src0, dst0, inv1, inv0, tcg, G);
    scan_block_kernel<<<cdiv(NG, 1024), 256, 0, stream>>>(G, bsum, NG);
    scan_bsum_kernel<<<1, 1024, 0, stream>>>(bsum, cdiv(NG, 1024));
    place_kernel<<<NBLK, 256, 0, stream>>>(
        src2, dst2, dst1, ew1, dst0, ew0, tcg, G, bsum, bedges);
    bucket_build_kernel<<<NB, 256, 0, stream>>>(bedges, G, bsum, rpre, csr, dis);
    disc_kernel<<<cdiv(NN2 + NN1, 256), 256, 0, stream>>>(perm1, perm0, dis, disc1, disc0);

    // ---- GIN layer 1: gather (hi-occ) -> fused MLP(64->64->64) + BN1 stats -
    gin_gather_kernel<false><<<cdiv((long)NN2 * 32, 256), 256, 0, stream>>>(
        xh, rpre, csr, nullptr, nullptr, nullptr, nullptr, t0f, NN2);
    mlp_gemm_kernel<64, 64, 64, true><<<cdiv(NN2, 64), 256, 0, stream>>>(
        t0f, W1a, b1a, W1b, b1b, s1, q1, t0h, NN2);

    // ---- GIN layer 2: gather (BN1 folded) -> fused MLP(64->128->128) -------
    gin_gather_kernel<true><<<cdiv((long)NN2 * 32, 256), 256, 0, stream>>>(
        t0h, rpre, csr, s1, q1, g1, bt1, t1, NN2);
    mlp_gemm_kernel<64, 128, 128, true><<<cdiv(NN2, 64), 256, 0, stream>>>(
        t1, W2a, b2a, W2b, b2b, s2, q2, Bb, NN2);

    // ---- GCN level 1: cmp1 = BN2(Bb) @ Wg0 (MFMA), gather -> out1 ----------
    mfma_gemm_kernel<128, 128, false, true, __half><<<cdiv(NN2, 64), 256, 0, stream>>>(
        Bb, Wg0, nullptr, s2, q2, g2, bt2, cmp1, NN2);
    gcn_gather128_kernel<true><<<cdiv((long)NN1 * 32, 256), 256, 0, stream>>>(
        cmp1, inv1, rpre + NN2, csr, disc1, dis, bg0, out1, NN1);

    // ---- GCN level 0: cmp0 = out1 @ Wg1 (MFMA), gather -> d_out ------------
    mfma_gemm_kernel<128, 64, false, false, __half><<<cdiv(NN1, 64), 256, 0, stream>>>(
        out1, Wg1, nullptr, nullptr, nullptr, nullptr, nullptr, cmp0, NN1);
    gcn_gather64_kernel<false><<<cdiv((long)NN0 * 16, 256), 256, 0, stream>>>(
        cmp0, inv0, rpre + NN2 + NN1, csr, disc0, dis + NN1, bg1, out, NN0);
}